// Round 10
// baseline (185.752 us; speedup 1.0000x reference)
//
#include <hip/hip_runtime.h>

// TrajLoss: sum over i of (x[i]-pred[i])^2 + (y[i]-pred[i+1])^2
// N = 16,777,216; pred has N+1 elements. Memory-bound streaming reduction.
//
// R5: algebraic re-split. Sum_i (y_i - p_{i+1})^2 == Sum_{j=1..N} (y_{j-1} - p_j)^2:
// thread owning pred[4i..4i+3] needs x4[i], p4[i] (aligned) and y[4i-1..4i+2].
// R6: all three streams nontemporal (zero reuse). 64.2 us.
// R7: grid 2048, persistent blocks, full unroll: 45.4 us (4.43 TB/s logical).
// R8: grid 1024, unroll 16: 42.6 us (4.7 TB/s). Few deep waves > many shallow.
// R9: grid 512 (2 blocks/CU, 32 chunks/thread, unroll 32) — last step on this
// axis. If regress, R8 is the sweet spot.

typedef float fx4 __attribute__((ext_vector_type(4)));

__global__ void TrajLoss_zero_kernel(float* out) {
    if (threadIdx.x == 0 && blockIdx.x == 0) out[0] = 0.0f;
}

__global__ __launch_bounds__(256) void TrajLoss_6141803233879_kernel(
    const float* __restrict__ pred,
    const float* __restrict__ x,
    const float* __restrict__ y,
    float* __restrict__ out,
    int n4,   // n / 4 (float4 count)
    int n)    // total elements
{
    const int tid    = blockIdx.x * blockDim.x + threadIdx.x;
    const int stride = gridDim.x * blockDim.x;

    float a0 = 0.0f, a1 = 0.0f, a2 = 0.0f, a3 = 0.0f;
    const fx4* x4 = (const fx4*)x;
    const fx4* p4 = (const fx4*)pred;

    int i = tid;

    if (tid == 0) {
        // Peel chunk 0 (rewrite terms j=0..3: dx_0..3, dy_1..3) + boundary j=N.
        float dx, dy;
        dx = x[0] - pred[0];                       a0 += dx*dx;
        dx = x[1] - pred[1]; dy = y[0] - pred[1];  a1 += dx*dx + dy*dy;
        dx = x[2] - pred[2]; dy = y[1] - pred[2];  a2 += dx*dx + dy*dy;
        dx = x[3] - pred[3]; dy = y[2] - pred[3];  a3 += dx*dx + dy*dy;
        if ((n & 3) == 0) {
            dy = y[n - 1] - pred[n];               a0 += dy*dy;   // rewrite j=N
        } else {
            // generic tail (dead for N=16.7M)
            dy = y[(n4 << 2) - 1] - pred[n4 << 2]; a0 += dy*dy;
            for (int j = n4 << 2; j < n; ++j) {
                dx = x[j] - pred[j];
                dy = y[j] - pred[j + 1];
                a0 += dx*dx + dy*dy;
            }
        }
        i += stride;   // thread 0 skips its first generic chunk (handled above)
    }

    #pragma unroll 32
    for (; i < n4; i += stride) {
        fx4 xv = __builtin_nontemporal_load(x4 + i);
        fx4 pa = __builtin_nontemporal_load(p4 + i);                 // pred[4i..4i+3]
        fx4 yb = __builtin_nontemporal_load((const fx4*)(y + (i << 2) - 1)); // y[4i-1..4i+2]
        float dx, dy;
        dx = xv.x - pa.x; dy = yb.x - pa.x; a0 += dx*dx + dy*dy;
        dx = xv.y - pa.y; dy = yb.y - pa.y; a1 += dx*dx + dy*dy;
        dx = xv.z - pa.z; dy = yb.z - pa.z; a2 += dx*dx + dy*dy;
        dx = xv.w - pa.w; dy = yb.w - pa.w; a3 += dx*dx + dy*dy;
    }

    float acc = (a0 + a1) + (a2 + a3);

    // Wave-64 reduce
    #pragma unroll
    for (int off = 32; off > 0; off >>= 1)
        acc += __shfl_down(acc, off, 64);

    __shared__ float smem[4];   // 256 threads = 4 waves
    const int lane = threadIdx.x & 63;
    const int wave = threadIdx.x >> 6;
    if (lane == 0) smem[wave] = acc;
    __syncthreads();

    if (threadIdx.x == 0) {
        float s = smem[0] + smem[1] + smem[2] + smem[3];
        atomicAdd(out, s);   // device-scope by default on gfx950
    }
}

extern "C" void kernel_launch(void* const* d_in, const int* in_sizes, int n_in,
                              void* d_out, int out_size, void* d_ws, size_t ws_size,
                              hipStream_t stream) {
    const float* pred = (const float*)d_in[0];   // N+1 floats
    const float* x    = (const float*)d_in[1];   // N floats
    const float* y    = (const float*)d_in[2];   // N floats
    float* out = (float*)d_out;

    const int n  = in_sizes[1];
    const int n4 = n >> 2;

    TrajLoss_zero_kernel<<<1, 64, 0, stream>>>(out);

    const int block = 256;
    // 512 blocks = 2 resident blocks/CU, persistent: 131,072 threads ->
    // exactly 32 float4 chunks/thread at N=16.7M.
    const int grid = 512;
    TrajLoss_6141803233879_kernel<<<grid, block, 0, stream>>>(pred, x, y, out, n4, n);
}

// Round 11
// 184.738 us; speedup vs baseline: 1.0055x; 1.0055x over previous
//
#include <hip/hip_runtime.h>

// TrajLoss: sum over i of (x[i]-pred[i])^2 + (y[i]-pred[i+1])^2
// N = 16,777,216; pred has N+1 elements. Memory-bound streaming reduction.
//
// R5: algebraic re-split. Sum_i (y_i - p_{i+1})^2 == Sum_{j=1..N} (y_{j-1} - p_j)^2:
// thread owning pred[4i..4i+3] needs x4[i], p4[i] (aligned) and y[4i-1..4i+2].
// R6: all three streams nontemporal (zero reuse). 64.2 us.
// R7: grid 2048 persistent: 45.4 us. R8: grid 1024, unroll 16: 42.6 us (best).
// R9: grid 512 regressed (47.7) -> occupancy curve mapped, 16 waves/CU optimal.
// R10: grid 1024 + MANUAL load batching. R9 showed the compiler caps batch
// depth (~VGPR 68-72 regardless of unroll). Explicit X[8]/P[8]/Y[8] arrays
// issue 24 nontemporal loads back-to-back per batch -> ~2x outstanding
// loads/wave at unchanged occupancy.

typedef float fx4 __attribute__((ext_vector_type(4)));

__global__ void TrajLoss_zero_kernel(float* out) {
    if (threadIdx.x == 0 && blockIdx.x == 0) out[0] = 0.0f;
}

__global__ __launch_bounds__(256) void TrajLoss_6141803233879_kernel(
    const float* __restrict__ pred,
    const float* __restrict__ x,
    const float* __restrict__ y,
    float* __restrict__ out,
    int n4,   // n / 4 (float4 count)
    int n)    // total elements
{
    const int tid    = blockIdx.x * blockDim.x + threadIdx.x;
    const int stride = gridDim.x * blockDim.x;

    float a0 = 0.0f, a1 = 0.0f, a2 = 0.0f, a3 = 0.0f;
    const fx4* x4 = (const fx4*)x;
    const fx4* p4 = (const fx4*)pred;

    int i = tid;

    if (tid == 0) {
        // Peel chunk 0 (rewrite terms j=0..3) + boundary j=N (+ generic tail).
        float dx, dy;
        dx = x[0] - pred[0];                       a0 += dx*dx;
        dx = x[1] - pred[1]; dy = y[0] - pred[1];  a1 += dx*dx + dy*dy;
        dx = x[2] - pred[2]; dy = y[1] - pred[2];  a2 += dx*dx + dy*dy;
        dx = x[3] - pred[3]; dy = y[2] - pred[3];  a3 += dx*dx + dy*dy;
        if ((n & 3) == 0) {
            dy = y[n - 1] - pred[n];               a0 += dy*dy;   // rewrite j=N
        } else {
            dy = y[(n4 << 2) - 1] - pred[n4 << 2]; a0 += dy*dy;
            for (int j = n4 << 2; j < n; ++j) {
                dx = x[j] - pred[j];
                dy = y[j] - pred[j + 1];
                a0 += dx*dx + dy*dy;
            }
        }
        i += stride;   // thread 0 skips its first generic chunk
    }

    // Batched main loop: 8 chunks per trip, all 24 loads issued before use.
    for (; i + 7 * stride < n4; i += 8 * stride) {
        fx4 X[8], P[8], Y[8];
        #pragma unroll
        for (int j = 0; j < 8; ++j) {
            const int idx = i + j * stride;
            X[j] = __builtin_nontemporal_load(x4 + idx);
            P[j] = __builtin_nontemporal_load(p4 + idx);
            Y[j] = __builtin_nontemporal_load((const fx4*)(y + (idx << 2) - 1));
        }
        #pragma unroll
        for (int j = 0; j < 8; ++j) {
            float dx, dy;
            dx = X[j].x - P[j].x; dy = Y[j].x - P[j].x; a0 += dx*dx + dy*dy;
            dx = X[j].y - P[j].y; dy = Y[j].y - P[j].y; a1 += dx*dx + dy*dy;
            dx = X[j].z - P[j].z; dy = Y[j].z - P[j].z; a2 += dx*dx + dy*dy;
            dx = X[j].w - P[j].w; dy = Y[j].w - P[j].w; a3 += dx*dx + dy*dy;
        }
    }

    // Remainder chunks (thread 0 after peel; any non-divisible shapes).
    for (; i < n4; i += stride) {
        fx4 xv = __builtin_nontemporal_load(x4 + i);
        fx4 pa = __builtin_nontemporal_load(p4 + i);
        fx4 yb = __builtin_nontemporal_load((const fx4*)(y + (i << 2) - 1));
        float dx, dy;
        dx = xv.x - pa.x; dy = yb.x - pa.x; a0 += dx*dx + dy*dy;
        dx = xv.y - pa.y; dy = yb.y - pa.y; a1 += dx*dx + dy*dy;
        dx = xv.z - pa.z; dy = yb.z - pa.z; a2 += dx*dx + dy*dy;
        dx = xv.w - pa.w; dy = yb.w - pa.w; a3 += dx*dx + dy*dy;
    }

    float acc = (a0 + a1) + (a2 + a3);

    // Wave-64 reduce
    #pragma unroll
    for (int off = 32; off > 0; off >>= 1)
        acc += __shfl_down(acc, off, 64);

    __shared__ float smem[4];   // 256 threads = 4 waves
    const int lane = threadIdx.x & 63;
    const int wave = threadIdx.x >> 6;
    if (lane == 0) smem[wave] = acc;
    __syncthreads();

    if (threadIdx.x == 0) {
        float s = smem[0] + smem[1] + smem[2] + smem[3];
        atomicAdd(out, s);   // device-scope by default on gfx950
    }
}

extern "C" void kernel_launch(void* const* d_in, const int* in_sizes, int n_in,
                              void* d_out, int out_size, void* d_ws, size_t ws_size,
                              hipStream_t stream) {
    const float* pred = (const float*)d_in[0];   // N+1 floats
    const float* x    = (const float*)d_in[1];   // N floats
    const float* y    = (const float*)d_in[2];   // N floats
    float* out = (float*)d_out;

    const int n  = in_sizes[1];
    const int n4 = n >> 2;

    TrajLoss_zero_kernel<<<1, 64, 0, stream>>>(out);

    const int block = 256;
    // 1024 blocks = 4 resident blocks/CU (16 waves/CU — R7/R8/R9 mapped this
    // as the occupancy sweet spot): 262,144 threads -> 16 chunks/thread,
    // processed as two 8-chunk batches.
    const int grid = 1024;
    TrajLoss_6141803233879_kernel<<<grid, block, 0, stream>>>(pred, x, y, out, n4, n);
}